// Round 2
// baseline (3201.799 us; speedup 1.0000x reference)
//
#include <hip/hip_runtime.h>
#include <math.h>

#define BB   32
#define CIN  32
#define COUT 64
#define HH   128
#define WW   128
#define PLANE (HH*WW)          // 16384

// symmetric padding index map (size 128, pad 2)
__device__ __forceinline__ int reflect(int p) {
    if (p < 0)   return -1 - p;      // -1->0, -2->1
    if (p > 127) return 255 - p;     // 128->127, 129->126
    return p;
}

// K0: repack weight [co][cin][kh][kw] -> wpk [(cin*25+k)][co]  (co fastest)
__global__ __launch_bounds__(256) void repack_w(const float* __restrict__ w,
                                                float* __restrict__ wpk) {
    int i = blockIdx.x * 256 + threadIdx.x;        // over 64*32*25 = 51200
    if (i >= COUT * CIN * 25) return;
    int co = i / (CIN * 25);
    int rm = i - co * (CIN * 25);                  // cin*25 + k
    wpk[rm * COUT + co] = w[i];
}

// K1: main 5x5 conv, symmetric pad.
// Block: 16 rows x 64 cols x 16 couts; 4 waves, each wave owns 4 rows.
// grid: (16 tiles [8 h-tiles x 2 w-tiles], 4 cout-blocks, 32 batch)
#define CI_C 4
__global__ __launch_bounds__(256) void conv_main(const float* __restrict__ x,
                                                 const float* __restrict__ wpk,
                                                 float* __restrict__ y1) {
    __shared__ float Xs[CI_C][20][68];             // 21760 B
    const int tid  = threadIdx.x;
    const int lane = tid & 63;                     // col within tile
    const int wv   = tid >> 6;                     // wave 0..3 -> rows 4wv..4wv+3
    const int tile = blockIdx.x;
    const int h0   = (tile >> 1) * 16;
    const int w0   = (tile & 1) * 64;
    const int cob  = blockIdx.y * 16;
    const int b    = blockIdx.z;

    float acc[4][16];
#pragma unroll
    for (int r = 0; r < 4; ++r)
#pragma unroll
        for (int c = 0; c < 16; ++c) acc[r][c] = 0.f;

    const float* xb = x + (size_t)b * CIN * PLANE;

    for (int cc = 0; cc < CIN; cc += CI_C) {
        __syncthreads();                           // previous chunk reads done
        for (int ci = 0; ci < CI_C; ++ci) {
            const float* xc = xb + (size_t)(cc + ci) * PLANE;
            for (int e = tid; e < 20 * 68; e += 256) {
                int r   = e / 68;
                int col = e - r * 68;
                int sh  = reflect(h0 - 2 + r);
                int sw  = reflect(w0 - 2 + col);
                Xs[ci][r][col] = xc[sh * WW + sw];
            }
        }
        __syncthreads();
#pragma unroll 1
        for (int ci = 0; ci < CI_C; ++ci) {
            const int cin = cc + ci;
            float xr[8][5];                        // rows 4wv..4wv+7, cols lane..lane+4
            // preload rows 0..3
#pragma unroll
            for (int q = 0; q < 4; ++q)
#pragma unroll
                for (int kw = 0; kw < 5; ++kw)
                    xr[q][kw] = Xs[ci][4 * wv + q][lane + kw];
#pragma unroll
            for (int kh = 0; kh < 5; ++kh) {
                if (kh > 0) {                      // load row kh+3 just before use
#pragma unroll
                    for (int kw = 0; kw < 5; ++kw)
                        xr[kh + 3][kw] = Xs[ci][4 * wv + kh + 3][lane + kw];
                }
                const float* wr = wpk + (size_t)((cin * 5 + kh) * 5) * COUT + cob;
#pragma unroll
                for (int kw = 0; kw < 5; ++kw) {
#pragma unroll
                    for (int c = 0; c < 16; ++c) {
                        float wt = wr[kw * COUT + c];   // block-uniform -> s_load
#pragma unroll
                        for (int rr = 0; rr < 4; ++rr)
                            acc[rr][c] = fmaf(xr[rr + kh][kw], wt, acc[rr][c]);
                    }
                }
            }
        }
    }

    float* yb = y1 + ((size_t)b * COUT + cob) * PLANE;
#pragma unroll
    for (int rr = 0; rr < 4; ++rr) {
        int hh = h0 + 4 * wv + rr;
#pragma unroll
        for (int c = 0; c < 16; ++c)
            yb[(size_t)c * PLANE + hh * WW + (w0 + lane)] = acc[rr][c];
    }
}

// K2: fused depthwise 5x5 DoG (zero pad SAME) + winner-take-all mask.
// Block: 4 rows x 64 cols of pixels, 1 thread/pixel; all 64 channels in regs.
// grid: (64 tiles [32 row-bands x 2 col-bands], 32 batch)
__global__ __launch_bounds__(256) void dog_wta(const float* __restrict__ y1,
                                               float* __restrict__ out) {
    __shared__ float Ys[8][8][68];                 // 17408 B
    __shared__ float dk[25];
    const int tid = threadIdx.x;
    if (tid < 25) {
        int i = tid / 5, j = tid % 5;
        double dx = i - 2, dy = j - 2;
        double r2 = dx * dx + dy * dy;
        const double se2 = 2.0 * 1.2 * 1.2, si2 = 2.0 * 1.4 * 1.4;
        const double pi2 = 3.14159265358979323846 * 2.0;
        double ge = exp(-r2 / se2) / (pi2 * 0.5 * se2);
        double gi = exp(-r2 / si2) / (pi2 * 0.5 * si2);
        double c0 = 1.0 / (pi2 * 0.5 * se2) - 1.0 / (pi2 * 0.5 * si2);
        dk[tid] = (float)((ge - gi) / c0);
    }
    const int col = tid & 63;
    const int rr  = tid >> 6;                      // 0..3
    const int h0  = (blockIdx.x >> 1) * 4;
    const int w0  = (blockIdx.x & 1) * 64;
    const int b   = blockIdx.y;
    const float* yb = y1 + (size_t)b * COUT * PLANE;

    float v[COUT];
#pragma unroll
    for (int c8 = 0; c8 < COUT; c8 += 8) {         // fully unrolled: static v[] idx
        __syncthreads();                           // prev chunk reads done (also dk)
        for (int e = tid; e < 8 * 8 * 68; e += 256) {
            int ci = e / 544;
            int rm = e - ci * 544;
            int r  = rm / 68;
            int cl = rm - r * 68;
            int sh = h0 - 2 + r, sw = w0 - 2 + cl;
            float val = 0.f;
            if ((unsigned)sh < HH && (unsigned)sw < WW)
                val = yb[(size_t)(c8 + ci) * PLANE + sh * WW + sw];
            Ys[ci][r][cl] = val;
        }
        __syncthreads();
#pragma unroll
        for (int ci = 0; ci < 8; ++ci) {
            float s = 0.f;
#pragma unroll
            for (int kh = 0; kh < 5; ++kh)
#pragma unroll
                for (int kw = 0; kw < 5; ++kw)
                    s = fmaf(Ys[ci][rr + kh][col + kw], dk[kh * 5 + kw], s);
            v[c8 + ci] = s;
        }
    }

    float m = -INFINITY;
#pragma unroll
    for (int c = 0; c < COUT; ++c) m = fmaxf(m, v[c]);

    float* ob = out + (size_t)b * COUT * PLANE + (h0 + rr) * WW + (w0 + col);
#pragma unroll
    for (int c = 0; c < COUT; ++c)
        ob[(size_t)c * PLANE] = (v[c] >= m) ? v[c] : 0.f;
}

extern "C" void kernel_launch(void* const* d_in, const int* in_sizes, int n_in,
                              void* d_out, int out_size, void* d_ws, size_t ws_size,
                              hipStream_t stream) {
    const float* x = (const float*)d_in[0];        // [32,32,128,128]
    const float* w = (const float*)d_in[1];        // [64,32,5,5]
    float* out = (float*)d_out;                    // [32,64,128,128]

    float* y1  = (float*)d_ws;                     // 134217728 B
    float* wpk = (float*)((char*)d_ws + (size_t)BB * COUT * PLANE * 4);

    repack_w<<<(COUT * CIN * 25 + 255) / 256, 256, 0, stream>>>(w, wpk);
    conv_main<<<dim3(16, 4, BB), 256, 0, stream>>>(x, wpk, y1);
    dog_wta<<<dim3(64, BB), 256, 0, stream>>>(y1, out);
}

// Round 3
// 791.485 us; speedup vs baseline: 4.0453x; 4.0453x over previous
//
#include <hip/hip_runtime.h>
#include <math.h>

#define BB   32
#define CIN  32
#define COUT 64
#define HH   128
#define WW   128
#define PLANE (HH*WW)          // 16384

// symmetric padding index map (size 128, pad 2)
__device__ __forceinline__ int reflect(int p) {
    if (p < 0)   return -1 - p;      // -1->0, -2->1
    if (p > 127) return 255 - p;     // 128->127, 129->126
    return p;
}

// K0: repack weight [co][cin][kh][kw] -> wpk [(cin*25+k)][co]  (co fastest)
__global__ __launch_bounds__(256) void repack_w(const float* __restrict__ w,
                                                float* __restrict__ wpk) {
    int i = blockIdx.x * 256 + threadIdx.x;        // over 64*32*25 = 51200
    if (i >= COUT * CIN * 25) return;
    int co = i / (CIN * 25);
    int rm = i - co * (CIN * 25);                  // cin*25 + k
    wpk[rm * COUT + co] = w[i];
}

// K1: main 5x5 conv, symmetric pad.
// Block: 8 rows x 64 cols x 32 couts; 4 waves, wave wv owns out rows 2wv,2wv+1.
// Each thread: acc[2][32] (2 rows x 32 couts).  ~100 VGPR, below spill cliff.
// grid: (32 tiles [16 h-tiles x 2 w-tiles], 2 cout-blocks, 32 batch)
__global__ __launch_bounds__(256) void conv_main(const float* __restrict__ x,
                                                 const float* __restrict__ wpk,
                                                 float* __restrict__ y1) {
    __shared__ float Xs[8][12][68];                // 26112 B
    const int tid  = threadIdx.x;
    const int lane = tid & 63;                     // col within tile
    const int wv   = tid >> 6;                     // wave 0..3
    const int tile = blockIdx.x;
    const int h0   = (tile >> 1) * 8;
    const int w0   = (tile & 1) * 64;
    const int cob  = blockIdx.y * 32;
    const int b    = blockIdx.z;

    float acc[2][32];
#pragma unroll
    for (int r = 0; r < 2; ++r)
#pragma unroll
        for (int c = 0; c < 32; ++c) acc[r][c] = 0.f;

    const float* xb = x + (size_t)b * CIN * PLANE;

    // ---- division-free staging precompute (hoisted out of all loops) ----
    // wave wv stages rows {wv, wv+4, wv+8}; cols: lane, plus 64+lane if lane<4
    int sh0 = reflect(h0 - 2 + wv) * WW;
    int sh1 = reflect(h0 - 2 + wv + 4) * WW;
    int sh2 = reflect(h0 - 2 + wv + 8) * WW;
    int sw0 = reflect(w0 - 2 + lane);
    int sw1 = (lane < 4) ? reflect(w0 + 62 + lane) : 0;

    for (int cc = 0; cc < CIN; cc += 8) {
        __syncthreads();                           // previous chunk reads done
#pragma unroll
        for (int ci = 0; ci < 8; ++ci) {
            const float* xc = xb + (size_t)(cc + ci) * PLANE;
            Xs[ci][wv][lane]     = xc[sh0 + sw0];
            Xs[ci][wv + 4][lane] = xc[sh1 + sw0];
            Xs[ci][wv + 8][lane] = xc[sh2 + sw0];
            if (lane < 4) {
                Xs[ci][wv][64 + lane]     = xc[sh0 + sw1];
                Xs[ci][wv + 4][64 + lane] = xc[sh1 + sw1];
                Xs[ci][wv + 8][64 + lane] = xc[sh2 + sw1];
            }
        }
        __syncthreads();
#pragma unroll 1
        for (int ci = 0; ci < 8; ++ci) {
            const int cin = cc + ci;
#pragma unroll
            for (int kh = 0; kh < 5; ++kh) {
                const int r0 = 2 * wv + kh;
                float x0[5], x1[5];
#pragma unroll
                for (int kw = 0; kw < 5; ++kw) {
                    x0[kw] = Xs[ci][r0][lane + kw];
                    x1[kw] = Xs[ci][r0 + 1][lane + kw];
                }
                const float* wr = wpk + (size_t)((cin * 5 + kh) * 5) * COUT + cob;
#pragma unroll
                for (int kw = 0; kw < 5; ++kw) {
#pragma unroll
                    for (int c = 0; c < 32; ++c) {
                        float wt = wr[kw * COUT + c];   // block-uniform -> s_load
                        acc[0][c] = fmaf(x0[kw], wt, acc[0][c]);
                        acc[1][c] = fmaf(x1[kw], wt, acc[1][c]);
                    }
                }
            }
        }
    }

    float* yb = y1 + ((size_t)b * COUT + cob) * PLANE;
#pragma unroll
    for (int rr = 0; rr < 2; ++rr) {
        int hh = h0 + 2 * wv + rr;
#pragma unroll
        for (int c = 0; c < 32; ++c)
            yb[(size_t)c * PLANE + hh * WW + (w0 + lane)] = acc[rr][c];
    }
}

// K2: depthwise 5x5 DoG, zero padding (SAME). Block: one (b,c) plane, 16 rows.
// grid: (8 h-tiles, 2048 b*c)   [R1-verified: no spills, ~130 us]
__global__ __launch_bounds__(256) void conv_dog(const float* __restrict__ y1,
                                                float* __restrict__ y2) {
    __shared__ float T[20][132];                   // 10560 B
    __shared__ float dogk[25];
    const int tid = threadIdx.x;
    if (tid < 25) {
        int i = tid / 5, j = tid % 5;
        double dx = i - 2, dy = j - 2;
        double r2 = dx * dx + dy * dy;
        const double se2 = 2.0 * 1.2 * 1.2, si2 = 2.0 * 1.4 * 1.4;
        const double tp  = 6.283185307179586476925;
        double ge = exp(-r2 / se2) / (tp * 0.5 * se2);
        double gi = exp(-r2 / si2) / (tp * 0.5 * si2);
        double c0 = 1.0 / (tp * 0.5 * se2) - 1.0 / (tp * 0.5 * si2);
        dogk[tid] = (float)((ge - gi) / c0);
    }
    const int bc = blockIdx.y;
    const int h0 = blockIdx.x * 16;
    const float* p = y1 + (size_t)bc * PLANE;
    for (int e = tid; e < 20 * 132; e += 256) {
        int r = e / 132, c = e - (e / 132) * 132;
        int sh = h0 - 2 + r, sw = c - 2;
        float v = 0.f;
        if (sh >= 0 && sh < HH && sw >= 0 && sw < WW) v = p[sh * WW + sw];
        T[r][c] = v;
    }
    __syncthreads();
    const int col = tid & 127;
    const int rr  = tid >> 7;                      // 0..1
    float* q = y2 + (size_t)bc * PLANE;
    for (int r8 = 0; r8 < 8; ++r8) {
        int r = rr * 8 + r8;                       // local out row 0..15
        float s = 0.f;
#pragma unroll
        for (int kh = 0; kh < 5; ++kh)
#pragma unroll
            for (int kw = 0; kw < 5; ++kw)
                s = fmaf(T[r + kh][col + kw], dogk[kh * 5 + kw], s);
        q[(h0 + r) * WW + col] = s;
    }
}

// K3: in-place winner-take-all over channels: out = y2 * (y2 == max_c y2)
// grid: 2048 blocks x 256 threads, one pixel (b,h,w) per thread
__global__ __launch_bounds__(256) void wta_mask(float* __restrict__ y) {
    int p   = blockIdx.x * 256 + threadIdx.x;      // 0 .. 524287
    int b   = p >> 14;
    int rem = p & 16383;
    float* base = y + (size_t)b * COUT * PLANE + rem;
    float v[COUT];
    float m = -INFINITY;
#pragma unroll
    for (int c = 0; c < COUT; ++c) {
        v[c] = base[(size_t)c * PLANE];
        m = fmaxf(m, v[c]);
    }
#pragma unroll
    for (int c = 0; c < COUT; ++c)
        base[(size_t)c * PLANE] = (v[c] >= m) ? v[c] : 0.f;
}

extern "C" void kernel_launch(void* const* d_in, const int* in_sizes, int n_in,
                              void* d_out, int out_size, void* d_ws, size_t ws_size,
                              hipStream_t stream) {
    const float* x = (const float*)d_in[0];        // [32,32,128,128]
    const float* w = (const float*)d_in[1];        // [64,32,5,5]
    float* out = (float*)d_out;                    // [32,64,128,128]

    float* y1  = (float*)d_ws;                     // 134217728 B
    float* wpk = (float*)((char*)d_ws + (size_t)BB * COUT * PLANE * 4);

    repack_w<<<(COUT * CIN * 25 + 255) / 256, 256, 0, stream>>>(w, wpk);
    conv_main<<<dim3(32, 2, BB), 256, 0, stream>>>(x, wpk, y1);
    conv_dog<<<dim3(8, BB * COUT), 256, 0, stream>>>(y1, out);
    wta_mask<<<(BB * PLANE) / 256, 256, 0, stream>>>(out);
}